// Round 2
// baseline (219.344 us; speedup 1.0000x reference)
//
#include <hip/hip_runtime.h>

// vanilla_lstm: B=256, V=32 -> N=8192 independent cells; T=48 encode + P=12 decode
// steps; F=4, H=128, gates=512. 256 blocks x 32 rows, 512 threads (8 waves).
// Wave w owns h-dims j in [16w, 16w+16) for all four gate groups -> i,f,g,o are
// lane-local in the MFMA C/D layout; c-state lives in registers; W_hh lives in
// VGPRs as bf16 B-fragments; h double-buffered in LDS (bf16, padded stride 136).

typedef __attribute__((ext_vector_type(8))) short short8;   // 8 x bf16 bits
typedef __attribute__((ext_vector_type(4))) float floatx4;

static __device__ __forceinline__ short f2bf(float x) {
  union { float f; unsigned u; } v; v.f = x;
  unsigned r = (v.u + 0x7FFFu + ((v.u >> 16) & 1u)) >> 16;  // RNE
  return (short)r;
}
static __device__ __forceinline__ float sigm(float x) {
  return __builtin_amdgcn_rcpf(1.0f + __expf(-x));
}
static __device__ __forceinline__ float tanh_(float x) {
  // tanh(x) = 1 - 2/(1+e^{2x}); saturates correctly at +/-inf via v_exp/v_rcp
  return 1.0f - 2.0f * __builtin_amdgcn_rcpf(1.0f + __expf(2.0f * x));
}

__global__ __launch_bounds__(512, 2) void lstm_fused(
    const float* __restrict__ seq,
    const float* __restrict__ W_ih, const float* __restrict__ W_hh,
    const float* __restrict__ b_ih, const float* __restrict__ b_hh,
    const float* __restrict__ W_out, const float* __restrict__ b_out,
    float* __restrict__ out)
{
  __shared__ __align__(16) short h_lds[2][32][136];  // bf16 bits, stride 136 (pad)
  __shared__ __align__(16) float x_buf[32][4];       // decode feedback x

  const int tid = threadIdx.x;
  const int w   = tid >> 6;      // wave 0..7 -> j-group
  const int L   = tid & 63;
  const int l15 = L & 15;
  const int l4  = L >> 4;        // 0..3
  const int base_row = blockIdx.x << 5;

  short8 frag1[4][4];   // W_hh B-frags [gate g][k-chunk kk]; col = 128g+16w+l15
  short8 wout[4];       // W_out B-frags, cols l15<4 valid else 0
  float  wih[4][4];     // W_ih[col][f] fp32
  float  bias[4];       // b_ih+b_hh per lane's col
  float  c_st[2][4];    // cell state, rows rg*16+4*l4+r, j = 16w+l15
  float  bo;

  // ---- init: zero h buffer 0 ----
  {
    short* hp = &h_lds[0][0][0];
    for (int i = tid; i < 32 * 136; i += 512) hp[i] = 0;
  }

  #pragma unroll
  for (int g = 0; g < 4; ++g) {
    const int col = g * 128 + w * 16 + l15;
    bias[g] = b_ih[col] + b_hh[col];
    #pragma unroll
    for (int f = 0; f < 4; ++f) wih[g][f] = W_ih[col * 4 + f];
    #pragma unroll
    for (int kk = 0; kk < 4; ++kk) {
      const float* src = W_hh + col * 128 + kk * 32 + l4 * 8;
      short8 fr;
      #pragma unroll
      for (int i = 0; i < 8; ++i) fr[i] = f2bf(src[i]);
      frag1[g][kk] = fr;
    }
  }
  bo = (l15 < 4) ? b_out[l15] : 0.0f;
  #pragma unroll
  for (int kk = 0; kk < 4; ++kk) {
    short8 fr;
    #pragma unroll
    for (int i = 0; i < 8; ++i)
      fr[i] = (l15 < 4) ? f2bf(W_out[l15 * 128 + kk * 32 + l4 * 8 + i]) : (short)0;
    wout[kk] = fr;
  }
  #pragma unroll
  for (int rg = 0; rg < 2; ++rg)
    #pragma unroll
    for (int r = 0; r < 4; ++r) c_st[rg][r] = 0.0f;

  __syncthreads();

  int cur = 0;

  // ===================== encode: t = 0..47 =====================
  for (int t = 0; t < 48; ++t) {
    #pragma unroll
    for (int rg = 0; rg < 2; ++rg) {
      short8 afr[4];
      #pragma unroll
      for (int kk = 0; kk < 4; ++kk)
        afr[kk] = *(const short8*)&h_lds[cur][rg * 16 + l15][kk * 32 + l4 * 8];

      floatx4 acc[4];
      #pragma unroll
      for (int g = 0; g < 4; ++g) acc[g] = (floatx4){bias[g], bias[g], bias[g], bias[g]};

      // x-projection in fp32 (K=4) straight into the accumulator
      #pragma unroll
      for (int r = 0; r < 4; ++r) {
        const int row = base_row + rg * 16 + l4 * 4 + r;
        const floatx4 x4 = *(const floatx4*)(seq + row * 192 + t * 4);
        #pragma unroll
        for (int g = 0; g < 4; ++g) {
          float s = acc[g][r];
          #pragma unroll
          for (int f = 0; f < 4; ++f) s = fmaf(x4[f], wih[g][f], s);
          acc[g][r] = s;
        }
      }

      #pragma unroll
      for (int g = 0; g < 4; ++g)
        #pragma unroll
        for (int kk = 0; kk < 4; ++kk)
          acc[g] = __builtin_amdgcn_mfma_f32_16x16x32_bf16(afr[kk], frag1[g][kk], acc[g], 0, 0, 0);

      #pragma unroll
      for (int r = 0; r < 4; ++r) {
        const float ig = sigm(acc[0][r]);
        const float fg = sigm(acc[1][r]);
        const float gg = tanh_(acc[2][r]);
        const float og = sigm(acc[3][r]);
        const float c  = fg * c_st[rg][r] + ig * gg;
        c_st[rg][r] = c;
        const float h = og * tanh_(c);
        h_lds[cur ^ 1][rg * 16 + l4 * 4 + r][w * 16 + l15] = f2bf(h);
      }
    }
    __syncthreads();
    cur ^= 1;
  }

  // ===================== decode: p = 0..11 =====================
  for (int p = 0; p < 12; ++p) {
    #pragma unroll
    for (int rg = 0; rg < 2; ++rg) {
      short8 afr[4];
      #pragma unroll
      for (int kk = 0; kk < 4; ++kk)
        afr[kk] = *(const short8*)&h_lds[cur][rg * 16 + l15][kk * 32 + l4 * 8];

      floatx4 acc[4];
      #pragma unroll
      for (int g = 0; g < 4; ++g) acc[g] = (floatx4){bias[g], bias[g], bias[g], bias[g]};

      #pragma unroll
      for (int r = 0; r < 4; ++r) {
        const int rloc = rg * 16 + l4 * 4 + r;
        floatx4 x4;
        if (p == 0) x4 = *(const floatx4*)(seq + (base_row + rloc) * 192 + 47 * 4);
        else        x4 = *(const floatx4*)&x_buf[rloc][0];
        #pragma unroll
        for (int g = 0; g < 4; ++g) {
          float s = acc[g][r];
          #pragma unroll
          for (int f = 0; f < 4; ++f) s = fmaf(x4[f], wih[g][f], s);
          acc[g][r] = s;
        }
      }

      #pragma unroll
      for (int g = 0; g < 4; ++g)
        #pragma unroll
        for (int kk = 0; kk < 4; ++kk)
          acc[g] = __builtin_amdgcn_mfma_f32_16x16x32_bf16(afr[kk], frag1[g][kk], acc[g], 0, 0, 0);

      #pragma unroll
      for (int r = 0; r < 4; ++r) {
        const float ig = sigm(acc[0][r]);
        const float fg = sigm(acc[1][r]);
        const float gg = tanh_(acc[2][r]);
        const float og = sigm(acc[3][r]);
        const float c  = fg * c_st[rg][r] + ig * gg;
        c_st[rg][r] = c;
        const float h = og * tanh_(c);
        h_lds[cur ^ 1][rg * 16 + l4 * 4 + r][w * 16 + l15] = f2bf(h);
      }
    }
    __syncthreads();   // h_new visible

    // out_p = h_new @ W_out^T + b_out  (wave 0 only; feeds x_buf + d_out)
    if (w == 0) {
      #pragma unroll
      for (int rg = 0; rg < 2; ++rg) {
        short8 afr[4];
        #pragma unroll
        for (int kk = 0; kk < 4; ++kk)
          afr[kk] = *(const short8*)&h_lds[cur ^ 1][rg * 16 + l15][kk * 32 + l4 * 8];
        floatx4 acco = (floatx4){bo, bo, bo, bo};
        #pragma unroll
        for (int kk = 0; kk < 4; ++kk)
          acco = __builtin_amdgcn_mfma_f32_16x16x32_bf16(afr[kk], wout[kk], acco, 0, 0, 0);
        if (l15 < 4) {
          #pragma unroll
          for (int r = 0; r < 4; ++r) {
            const int rloc = rg * 16 + l4 * 4 + r;
            out[(base_row + rloc) * 48 + p * 4 + l15] = acco[r];  // [B,V,P,F] flat
            x_buf[rloc][l15] = acco[r];
          }
        }
      }
    }
    __syncthreads();   // x_buf visible for next p
    cur ^= 1;
  }
}

extern "C" void kernel_launch(void* const* d_in, const int* in_sizes, int n_in,
                              void* d_out, int out_size, void* d_ws, size_t ws_size,
                              hipStream_t stream) {
  const float* seq   = (const float*)d_in[0];
  // d_in[1..5] (dist/bearing/heading matrices, masks) unused by the reference fwd
  const float* W_ih  = (const float*)d_in[6];
  const float* W_hh  = (const float*)d_in[7];
  const float* b_ih  = (const float*)d_in[8];
  const float* b_hh  = (const float*)d_in[9];
  const float* W_out = (const float*)d_in[10];
  const float* b_out = (const float*)d_in[11];
  lstm_fused<<<256, 512, 0, stream>>>(seq, W_ih, W_hh, b_ih, b_hh, W_out, b_out,
                                      (float*)d_out);
}